// Round 5
// baseline (641.918 us; speedup 1.0000x reference)
//
#include <hip/hip_runtime.h>
#include <math.h>

#define B_   8192
#define N_   68
#define FIN  2
#define F_   128
#define C_   16
#define E_   272

// d_out flat layout (fp32), reference tuple order:
#define OUT_OFF  0                              // [B,16,128]
#define ADJ_OFF  (B_*C_*F_)                     // [B,16,16]
#define LINK_IDX (ADJ_OFF + B_*C_*C_)
#define ENT_IDX  (LINK_IDX + 1)
#define POS_OFF  (ENT_IDX + 1)                  // [B,68,2]

// ws: [0,131072) partials (doubles, 8192*2)
//     [131072,+1364) csr ints
//     [133120,+131072) wcat bf16 (2 layers * 128 j * 256 k)
//     [264192,+20480) Ag bf16 [80][128] (graph multiplicity matrix)
#define WS_CSR_OFF  131072
#define WS_W_OFF    133120
#define WS_AG_OFF   264192

typedef __attribute__((ext_vector_type(8))) short bf16x8;
typedef __attribute__((ext_vector_type(4))) float f32x4;

// XOR swizzles (T2). SWZ256/512: row strides 256/512 B, 8-row spread.
// SWZH: row stride 192 B (HT [128][96]); XOR only bits 4-5 -> stays in-row.
#define SWZ256(r, cb) (((r) * 256) + ((cb) ^ (((r) & 7) << 4)))
#define SWZ512(r, cb) (((r) * 512) + ((cb) ^ (((r) & 7) << 4)))
#define SWZH(r, cb)   (((r) * 192) + ((cb) ^ (((r) & 3) << 4)))
#define MFMA16(a, bb, c) __builtin_amdgcn_mfma_f32_16x16x32_bf16((a), (bb), (c), 0, 0, 0)

__device__ __forceinline__ short bf16_rne(float x) {
  unsigned u = __builtin_bit_cast(unsigned, x);
  u += 0x7FFFu + ((u >> 16) & 1u);
  return (short)(u >> 16);
}

__global__ void prep_kernel(const int* __restrict__ edge_index,
                            const float* __restrict__ W2r, const float* __restrict__ W2o,
                            const float* __restrict__ W3r, const float* __restrict__ W3o,
                            int* __restrict__ csr, short* __restrict__ wcat,
                            short* __restrict__ agw) {
  // wcat[layer][j][k]: k<128 -> Wrel[j][k], k>=128 -> Wroot[j][k-128]
  int gid = blockIdx.x * blockDim.x + threadIdx.x;
  for (int e = gid; e < 2 * F_ * 256; e += gridDim.x * blockDim.x) {
    int layer = e >> 15, idx = e & 32767;
    int j = idx >> 8, k = idx & 255;
    const float* Wr = layer ? W3r : W2r;
    const float* Wo = layer ? W3o : W2o;
    float v = (k < F_) ? Wr[j * F_ + k] : Wo[j * F_ + (k - F_)];
    wcat[e] = bf16_rne(v);
  }
  __shared__ unsigned short cnt[80 * 128];
  __shared__ int src_s[E_], dst_s[E_], cc[N_], offs[N_ + 1];
  if (blockIdx.x == 0) {
    int t = threadIdx.x;
    for (int i = t; i < 80 * 128; i += blockDim.x) cnt[i] = 0;
    for (int e = t; e < E_; e += blockDim.x) { src_s[e] = edge_index[e]; dst_s[e] = edge_index[E_ + e]; }
    for (int n = t; n < N_; n += blockDim.x) cc[n] = 0;
    __syncthreads();
    if (t == 0) {
      for (int e = 0; e < E_; ++e) { cnt[dst_s[e] * 128 + src_s[e]]++; cc[dst_s[e]]++; }
      offs[0] = 0;
      for (int n = 0; n < N_; ++n) offs[n + 1] = offs[n] + cc[n];
      for (int n = 0; n < N_; ++n) cc[n] = offs[n];
      for (int e = 0; e < E_; ++e) { int d = dst_s[e]; csr[N_ + 1 + cc[d]++] = src_s[e]; }
      for (int n = 0; n <= N_; ++n) csr[n] = offs[n];
    }
    __syncthreads();
    for (int i = t; i < 80 * 128; i += blockDim.x) agw[i] = bf16_rne((float)cnt[i]);
  }
}

// A-fragment of adj (fp32 global -> bf16 regs), zero-masked K-pad (m >= 68)
__device__ __forceinline__ bf16x8 adj_frag(const float* __restrict__ rowp, int m0) {
  bf16x8 r;
#pragma unroll
  for (int i = 0; i < 8; ++i) {
    int m = m0 + i;
    float v = (m < N_) ? rowp[m] : 0.f;
    r[i] = bf16_rne(v);
  }
  return r;
}

__launch_bounds__(512, 4)
__global__ void fused_kernel(
    const float* __restrict__ x, const float* __restrict__ adj, const float* __restrict__ s,
    const float* __restrict__ pos,
    const float* __restrict__ W1r, const float* __restrict__ W1o, const float* __restrict__ b1,
    const float* __restrict__ b2f, const float* __restrict__ b3f,
    const short* __restrict__ wcat, const short* __restrict__ agw,
    float* __restrict__ out, const int* __restrict__ csr, double* __restrict__ partials)
{
  __shared__ __align__(16) short Hn[80 * 256];    // node-major cat: [n][0..127]=agg, [128..255]=h
  __shared__ __align__(16) short HT[128 * 96];    // feature-major h [f][n], stride 192B
  __shared__ __align__(16) short ssmT[16 * 128];  // softmax(s)^T [c][n], zero-padded
  __shared__ __align__(16) short TT[16 * 128];    // (adj@S)^T [c][n], zero-padded
  __shared__ float xb[N_ * FIN], axb[N_ * FIN];
  __shared__ int offs[N_ + 1], srcs[E_];
  __shared__ double red[16];

  const int b = blockIdx.x, tid = threadIdx.x;
  const int lane = tid & 63, wave = tid >> 6;
  const int l15 = lane & 15, lg = lane >> 4;
  const int f = tid & 127, ng = tid >> 7;
  const int j0 = wave * 16;

  // ---- P0: fills + pad-zeroing (disjoint LDS regions, one barrier) ----
  for (int i = tid; i < N_ + 1; i += 512) offs[i] = csr[i];
  for (int i = tid; i < E_; i += 512) srcs[i] = csr[N_ + 1 + i];
  for (int i = tid; i < N_ * FIN; i += 512) xb[i] = x[(size_t)b * N_ * FIN + i];
  // zero K-pads (0 x garbage = NaN hazard): HT cols [68,96), ssmT/TT cols [68,96)
  for (int i = tid; i < 128 * 28; i += 512) {
    int r = i / 28, n = 68 + i - (i / 28) * 28;
    *(short*)((char*)HT + SWZH(r, n * 2)) = 0;
  }
  for (int i = tid; i < 16 * 28; i += 512) {
    int r = i / 28, n = 68 + i - (i / 28) * 28;
    *(short*)((char*)ssmT + SWZ256(r, n * 2)) = 0;
    *(short*)((char*)TT + SWZ256(r, n * 2)) = 0;
  }
  // sum(adj^2) stream (also warms L2 for the P7 adj fragment reads)
  float sadj2 = 0.f;
  const float* adjb = &adj[(size_t)b * N_ * N_];
  for (int q = tid; q < N_ * N_; q += 512) {
    float v = adjb[q];
    sadj2 += v * v;
  }
  // softmax rows -> ssmT (bf16), ent via m + logZ - sum(p*s)
  float entPart = 0.f;
  if (tid < N_) {
    const float* srow = &s[((size_t)b * N_ + tid) * C_];
    float sv[16], ev[16];
    float mx = -1e30f;
#pragma unroll
    for (int c = 0; c < 16; ++c) { sv[c] = srow[c]; mx = fmaxf(mx, sv[c]); }
    float sum = 0.f;
#pragma unroll
    for (int c = 0; c < 16; ++c) { ev[c] = expf(sv[c] - mx); sum += ev[c]; }
    float inv = 1.f / sum, ps = 0.f;
#pragma unroll
    for (int c = 0; c < 16; ++c) {
      float pv = ev[c] * inv;
      ps += pv * sv[c];
      *(short*)((char*)ssmT + SWZ256(c, tid * 2)) = bf16_rne(pv);
    }
    entPart = (mx + logf(sum)) - ps;
  }
  // pos passthrough (independent)
  for (int i = tid; i < N_ * FIN; i += 512)
    out[POS_OFF + (size_t)b * N_ * FIN + i] = pos[(size_t)b * N_ * FIN + i];
  __syncthreads();

  // ---- P1: layer-1 edge aggregation on [68,2] (tiny, VALU) ----
  if (tid < N_) {
    float a0 = 0, a1 = 0;
    for (int e = offs[tid]; e < offs[tid + 1]; ++e) {
      int sr = srcs[e];
      a0 += xb[sr * 2]; a1 += xb[sr * 2 + 1];
    }
    axb[tid * 2] = a0; axb[tid * 2 + 1] = a1;
  }
  __syncthreads();

  // ---- P2: layer 1 (K=2, VALU) -> Hn root-half + HT ----
  {
    float wr0 = W1r[f * 2], wr1 = W1r[f * 2 + 1];
    float wo0 = W1o[f * 2], wo1 = W1o[f * 2 + 1];
    float bv = b1[f];
    for (int i = 0; i < 17; ++i) {
      int n = ng * 17 + i;
      float v = axb[n * 2] * wr0 + axb[n * 2 + 1] * wr1 + xb[n * 2] * wo0 + xb[n * 2 + 1] * wo1 + bv;
      v = v > 0.f ? v : 0.f;
      short hv = bf16_rne(v);
      *(short*)((char*)Hn + SWZ512(n, 256 + f * 2)) = hv;
      *(short*)((char*)HT + SWZH(f, n * 2)) = hv;
    }
  }
  __syncthreads();

  // ---- P3: agg2 = Ag @ h1 (MFMA; Ag A-frags direct from global) -> Hn agg-half ----
  {
    bf16x8 Bh[3];
#pragma unroll
    for (int ks = 0; ks < 3; ++ks)
      Bh[ks] = *(const bf16x8*)((const char*)HT + SWZH(j0 + l15, ks * 64 + 16 * lg));
#pragma unroll
    for (int mt = 0; mt < 5; ++mt) {
      f32x4 acc = {0.f, 0.f, 0.f, 0.f};
#pragma unroll
      for (int ks = 0; ks < 3; ++ks)
        acc = MFMA16(*(const bf16x8*)(agw + (mt * 16 + l15) * 128 + ks * 32 + lg * 8), Bh[ks], acc);
#pragma unroll
      for (int r = 0; r < 4; ++r) {
        int n = mt * 16 + lg * 4 + r;
        if (n < N_) *(short*)((char*)Hn + SWZ512(n, (j0 + l15) * 2)) = bf16_rne(acc[r]);
      }
    }
  }
  __syncthreads();

  // ---- P4: layer 2 (MFMA, K=256), deferred epilogue -> Hn root + HT ----
  {
    f32x4 accL[5];
    bf16x8 Bw[8];
#pragma unroll
    for (int ks = 0; ks < 8; ++ks)
      Bw[ks] = *(const bf16x8*)(wcat + (j0 + l15) * 256 + ks * 32 + 8 * lg);
#pragma unroll
    for (int mt = 0; mt < 5; ++mt) {
      f32x4 acc = {0.f, 0.f, 0.f, 0.f};
#pragma unroll
      for (int ks = 0; ks < 8; ++ks)
        acc = MFMA16(*(const bf16x8*)((const char*)Hn + SWZ512(mt * 16 + l15, ks * 64 + 16 * lg)), Bw[ks], acc);
      accL[mt] = acc;
    }
    __syncthreads();   // all Hn reads done
    float bv = b2f[j0 + l15];
#pragma unroll
    for (int mt = 0; mt < 5; ++mt)
#pragma unroll
      for (int r = 0; r < 4; ++r) {
        int n = mt * 16 + lg * 4 + r;
        if (n < N_) {
          float v = accL[mt][r] + bv;
          v = v > 0.f ? v : 0.f;
          short hv = bf16_rne(v);
          *(short*)((char*)Hn + SWZ512(n, 256 + (j0 + l15) * 2)) = hv;
          *(short*)((char*)HT + SWZH(j0 + l15, n * 2)) = hv;
        }
      }
  }
  __syncthreads();

  // ---- P5: agg3 = Ag @ h2 -> Hn agg-half ----
  {
    bf16x8 Bh[3];
#pragma unroll
    for (int ks = 0; ks < 3; ++ks)
      Bh[ks] = *(const bf16x8*)((const char*)HT + SWZH(j0 + l15, ks * 64 + 16 * lg));
#pragma unroll
    for (int mt = 0; mt < 5; ++mt) {
      f32x4 acc = {0.f, 0.f, 0.f, 0.f};
#pragma unroll
      for (int ks = 0; ks < 3; ++ks)
        acc = MFMA16(*(const bf16x8*)(agw + (mt * 16 + l15) * 128 + ks * 32 + lg * 8), Bh[ks], acc);
#pragma unroll
      for (int r = 0; r < 4; ++r) {
        int n = mt * 16 + lg * 4 + r;
        if (n < N_) *(short*)((char*)Hn + SWZ512(n, (j0 + l15) * 2)) = bf16_rne(acc[r]);
      }
    }
  }
  __syncthreads();

  // ---- P6: layer 3 (MFMA), deferred epilogue -> HT only (h3) ----
  {
    f32x4 accL[5];
    bf16x8 Bw[8];
#pragma unroll
    for (int ks = 0; ks < 8; ++ks)
      Bw[ks] = *(const bf16x8*)(wcat + 32768 + (j0 + l15) * 256 + ks * 32 + 8 * lg);
#pragma unroll
    for (int mt = 0; mt < 5; ++mt) {
      f32x4 acc = {0.f, 0.f, 0.f, 0.f};
#pragma unroll
      for (int ks = 0; ks < 8; ++ks)
        acc = MFMA16(*(const bf16x8*)((const char*)Hn + SWZ512(mt * 16 + l15, ks * 64 + 16 * lg)), Bw[ks], acc);
      accL[mt] = acc;
    }
    __syncthreads();
    float bv = b3f[j0 + l15];
#pragma unroll
    for (int mt = 0; mt < 5; ++mt)
#pragma unroll
      for (int r = 0; r < 4; ++r) {
        int n = mt * 16 + lg * 4 + r;
        if (n < N_) {
          float v = accL[mt][r] + bv;
          v = v > 0.f ? v : 0.f;
          *(short*)((char*)HT + SWZH(j0 + l15, n * 2)) = bf16_rne(v);
        }
      }
  }
  __syncthreads();

  // ---- P7: pooling MFMAs ----
  float trPart = 0.f, g2Part = 0.f;
  {
    // pooled out (all waves): outT[f][c] = sum_n h3T[f][n] * S[n][c]
    f32x4 acc = {0.f, 0.f, 0.f, 0.f};
#pragma unroll
    for (int ks = 0; ks < 3; ++ks)
      acc = MFMA16(*(const bf16x8*)((const char*)HT + SWZH(j0 + l15, ks * 64 + 16 * lg)),
                   *(const bf16x8*)((const char*)ssmT + SWZ256(l15, ks * 64 + 16 * lg)), acc);
    float4 st; st.x = acc[0]; st.y = acc[1]; st.z = acc[2]; st.w = acc[3];
    *(float4*)&out[OUT_OFF + (size_t)b * C_ * F_ + l15 * F_ + j0 + lg * 4] = st;
  }
  if (wave < 5) {
    // T = adj @ S -> TT[c][n]; adj A-frags direct from global (row clamp for OOB)
    int row = wave * 16 + l15;
    const float* rowp = adjb + (size_t)(row < N_ ? row : 0) * N_;
    f32x4 acc = {0.f, 0.f, 0.f, 0.f};
#pragma unroll
    for (int ks = 0; ks < 3; ++ks)
      acc = MFMA16(adj_frag(rowp, ks * 32 + lg * 8),
                   *(const bf16x8*)((const char*)ssmT + SWZ256(l15, ks * 64 + 16 * lg)), acc);
#pragma unroll
    for (int r = 0; r < 4; ++r) {
      int n = wave * 16 + lg * 4 + r;
      if (n < N_) *(short*)((char*)TT + SWZ256(l15, n * 2)) = bf16_rne(acc[r]);
    }
  } else if (wave == 5) {
    // G = S^T S ; ||G||_F^2
    f32x4 acc = {0.f, 0.f, 0.f, 0.f};
#pragma unroll
    for (int ks = 0; ks < 3; ++ks) {
      bf16x8 a = *(const bf16x8*)((const char*)ssmT + SWZ256(l15, ks * 64 + 16 * lg));
      acc = MFMA16(a, a, acc);
    }
#pragma unroll
    for (int r = 0; r < 4; ++r) g2Part += acc[r] * acc[r];
  }
  __syncthreads();

  // ---- P8: out_adj = S^T T (wave 0) + trace ----
  if (wave == 0) {
    f32x4 acc = {0.f, 0.f, 0.f, 0.f};
#pragma unroll
    for (int ks = 0; ks < 3; ++ks)
      acc = MFMA16(*(const bf16x8*)((const char*)ssmT + SWZ256(l15, ks * 64 + 16 * lg)),
                   *(const bf16x8*)((const char*)TT + SWZ256(l15, ks * 64 + 16 * lg)), acc);
#pragma unroll
    for (int r = 0; r < 4; ++r) {
      int c = lg * 4 + r;
      out[ADJ_OFF + (size_t)b * 256 + c * 16 + l15] = acc[r];
      if (c == l15) trPart += acc[r];
    }
  }

  // ---- P9: loss reductions: link = sum(adj^2) - 2*tr + ||G||^2 ----
  double lk = (double)sadj2 - 2.0 * (double)trPart + (double)g2Part;
  double en = (double)entPart;
  for (int o = 32; o > 0; o >>= 1) { lk += __shfl_down(lk, o); en += __shfl_down(en, o); }
  if ((tid & 63) == 0) { red[wave] = lk; red[8 + wave] = en; }
  __syncthreads();
  if (tid == 0) {
    double L = 0, En = 0;
    for (int w = 0; w < 8; ++w) { L += red[w]; En += red[8 + w]; }
    partials[2 * b] = L;
    partials[2 * b + 1] = En;
  }
}

__global__ void finalize_kernel(const double* __restrict__ partials, float* __restrict__ out) {
  __shared__ double red[16];
  int tid = threadIdx.x;
  double L = 0, En = 0;
  for (int i = tid; i < B_; i += 512) { L += partials[2 * i]; En += partials[2 * i + 1]; }
  for (int o = 32; o > 0; o >>= 1) { L += __shfl_down(L, o); En += __shfl_down(En, o); }
  if ((tid & 63) == 0) { red[tid >> 6] = L; red[8 + (tid >> 6)] = En; }
  __syncthreads();
  if (tid == 0) {
    double Ls = 0, Es = 0;
    for (int w = 0; w < 8; ++w) { Ls += red[w]; Es += red[8 + w]; }
    out[LINK_IDX] = (float)(sqrt(Ls) / (double)((size_t)B_ * N_ * N_));
    out[ENT_IDX] = (float)(Es / (double)((size_t)B_ * N_));
  }
}

extern "C" void kernel_launch(void* const* d_in, const int* in_sizes, int n_in,
                              void* d_out, int out_size, void* d_ws, size_t ws_size,
                              hipStream_t stream) {
  const float* x   = (const float*)d_in[0];
  const int*   ei  = (const int*)d_in[1];
  const float* adj = (const float*)d_in[2];
  const float* s   = (const float*)d_in[3];
  const float* pos = (const float*)d_in[4];
  const float* W1r = (const float*)d_in[5];
  const float* W1o = (const float*)d_in[6];
  const float* b1  = (const float*)d_in[7];
  const float* W2r = (const float*)d_in[8];
  const float* W2o = (const float*)d_in[9];
  const float* b2  = (const float*)d_in[10];
  const float* W3r = (const float*)d_in[11];
  const float* W3o = (const float*)d_in[12];
  const float* b3  = (const float*)d_in[13];

  float* out = (float*)d_out;
  double* partials = (double*)d_ws;
  int* csr = (int*)((char*)d_ws + WS_CSR_OFF);
  short* wcat = (short*)((char*)d_ws + WS_W_OFF);
  short* agw  = (short*)((char*)d_ws + WS_AG_OFF);

  prep_kernel<<<65, 512, 0, stream>>>(ei, W2r, W2o, W3r, W3o, csr, wcat, agw);
  fused_kernel<<<B_, 512, 0, stream>>>(x, adj, s, pos, W1r, W1o, b1, b2, b3,
                                       wcat, agw, out, csr, partials);
  finalize_kernel<<<1, 512, 0, stream>>>(partials, out);
}

// Round 6
// 591.201 us; speedup vs baseline: 1.0858x; 1.0858x over previous
//
#include <hip/hip_runtime.h>
#include <math.h>

#define B_   8192
#define N_   68
#define FIN  2
#define F_   128
#define C_   16
#define E_   272

// d_out flat layout (fp32), reference tuple order:
#define OUT_OFF  0                              // [B,16,128]
#define ADJ_OFF  (B_*C_*F_)                     // [B,16,16]
#define LINK_IDX (ADJ_OFF + B_*C_*C_)
#define ENT_IDX  (LINK_IDX + 1)
#define POS_OFF  (ENT_IDX + 1)                  // [B,68,2]

// ws: [0,131072) partials (doubles, 8192*2)
//     [131072,+1364) csr ints
//     [133120,+131072) wcat bf16 (2 layers * 128 j * 256 k)
//     [264192,+20480) Ag bf16 [80][128] (graph multiplicity matrix, zero rows/cols >= 68)
#define WS_CSR_OFF  131072
#define WS_W_OFF    133120
#define WS_AG_OFF   264192

typedef __attribute__((ext_vector_type(8))) short bf16x8;
typedef __attribute__((ext_vector_type(4))) float f32x4;

// XOR swizzles (T2). Row strides 512/256/192 B; XOR bits 4-5 only -> 8B/16B blocks preserved.
#define SWZ256(r, cb) (((r) * 256) + ((cb) ^ (((r) & 7) << 4)))
#define SWZ512(r, cb) (((r) * 512) + ((cb) ^ (((r) & 7) << 4)))
#define SWZH(r, cb)   (((r) * 192) + ((cb) ^ (((r) & 3) << 4)))
#define MFMA16(a, bb, c) __builtin_amdgcn_mfma_f32_16x16x32_bf16((a), (bb), (c), 0, 0, 0)

__device__ __forceinline__ short bf16_rne(float x) {
  unsigned u = __builtin_bit_cast(unsigned, x);
  u += 0x7FFFu + ((u >> 16) & 1u);
  return (short)(u >> 16);
}

// pack f32x4 -> 4 bf16 (8 bytes)
__device__ __forceinline__ short4 pack4(f32x4 v) {
  short4 s;
  s.x = bf16_rne(v[0]); s.y = bf16_rne(v[1]); s.z = bf16_rne(v[2]); s.w = bf16_rne(v[3]);
  return s;
}

__global__ void prep_kernel(const int* __restrict__ edge_index,
                            const float* __restrict__ W2r, const float* __restrict__ W2o,
                            const float* __restrict__ W3r, const float* __restrict__ W3o,
                            int* __restrict__ csr, short* __restrict__ wcat,
                            short* __restrict__ agw) {
  // wcat[layer][j][k]: k<128 -> Wrel[j][k], k>=128 -> Wroot[j][k-128]
  int gid = blockIdx.x * blockDim.x + threadIdx.x;
  for (int e = gid; e < 2 * F_ * 256; e += gridDim.x * blockDim.x) {
    int layer = e >> 15, idx = e & 32767;
    int j = idx >> 8, k = idx & 255;
    const float* Wr = layer ? W3r : W2r;
    const float* Wo = layer ? W3o : W2o;
    float v = (k < F_) ? Wr[j * F_ + k] : Wo[j * F_ + (k - F_)];
    wcat[e] = bf16_rne(v);
  }
  __shared__ unsigned short cnt[80 * 128];
  __shared__ int src_s[E_], dst_s[E_], cc[N_], offs[N_ + 1];
  if (blockIdx.x == 0) {
    int t = threadIdx.x;
    for (int i = t; i < 80 * 128; i += blockDim.x) cnt[i] = 0;
    for (int e = t; e < E_; e += blockDim.x) { src_s[e] = edge_index[e]; dst_s[e] = edge_index[E_ + e]; }
    for (int n = t; n < N_; n += blockDim.x) cc[n] = 0;
    __syncthreads();
    if (t == 0) {
      for (int e = 0; e < E_; ++e) { cnt[dst_s[e] * 128 + src_s[e]]++; cc[dst_s[e]]++; }
      offs[0] = 0;
      for (int n = 0; n < N_; ++n) offs[n + 1] = offs[n] + cc[n];
      for (int n = 0; n < N_; ++n) cc[n] = offs[n];
      for (int e = 0; e < E_; ++e) { int d = dst_s[e]; csr[N_ + 1 + cc[d]++] = src_s[e]; }
      for (int n = 0; n <= N_; ++n) csr[n] = offs[n];
    }
    __syncthreads();
    for (int i = t; i < 80 * 128; i += blockDim.x) agw[i] = bf16_rne((float)cnt[i]);
  }
}

// A-fragment of adj (fp32 global -> bf16 regs), zero-masked K-pad (m >= 68)
__device__ __forceinline__ bf16x8 adj_frag(const float* __restrict__ rowp, int m0) {
  bf16x8 r;
#pragma unroll
  for (int i = 0; i < 8; ++i) {
    int m = m0 + i;
    float v = (m < N_) ? rowp[m] : 0.f;
    r[i] = bf16_rne(v);
  }
  return r;
}

__launch_bounds__(512, 4)
__global__ void fused_kernel(
    const float* __restrict__ x, const float* __restrict__ adj, const float* __restrict__ s,
    const float* __restrict__ pos,
    const float* __restrict__ W1r, const float* __restrict__ W1o, const float* __restrict__ b1,
    const float* __restrict__ b2f, const float* __restrict__ b3f,
    const short* __restrict__ wcat, const short* __restrict__ agw,
    float* __restrict__ out, const int* __restrict__ csr, double* __restrict__ partials)
{
  __shared__ __align__(16) short Hn[80 * 256];    // node-major cat: [n][0..127]=agg, [128..255]=h
  __shared__ __align__(16) short HT[128 * 96];    // feature-major h [f][n], stride 192B
  __shared__ __align__(16) short ssmT[16 * 128];  // softmax(s)^T [c][n], zero-padded n>=68
  __shared__ __align__(16) short TT[16 * 128];    // (adj@S)^T [c][n], zero-padded n>=68
  __shared__ float xb[N_ * FIN], axb[N_ * FIN];
  __shared__ int offs[N_ + 1], srcs[E_];
  __shared__ double red[16];

  const int b = blockIdx.x, tid = threadIdx.x;
  const int lane = tid & 63, wave = tid >> 6;
  const int l15 = lane & 15, lg = lane >> 4;
  const int f = tid & 127, ng = tid >> 7;
  const int j0 = wave * 16;

  // ---- P0: fills + pad-zeroing (disjoint LDS regions, one barrier) ----
  for (int i = tid; i < N_ + 1; i += 512) offs[i] = csr[i];
  for (int i = tid; i < E_; i += 512) srcs[i] = csr[N_ + 1 + i];
  for (int i = tid; i < N_ * FIN; i += 512) xb[i] = x[(size_t)b * N_ * FIN + i];
  // zero Hn rows 68-79 fully (12 rows x 512B = 384 x b128)
  {
    int4 zz; zz.x = 0; zz.y = 0; zz.z = 0; zz.w = 0;
    for (int i = tid; i < 384; i += 512) {
      int r = 68 + (i >> 5), cb = (i & 31) * 16;
      *(int4*)((char*)Hn + SWZ512(r, cb)) = zz;
    }
    // zero HT cols [68,96): bytes 136..191, 7 b64 per row x 128 rows
    long long z8 = 0;
    for (int i = tid; i < 128 * 7; i += 512) {
      int r = i / 7, cb = 136 + (i - (i / 7) * 7) * 8;
      *(long long*)((char*)HT + SWZH(r, cb)) = z8;
    }
    // zero ssmT/TT cols [68,96): 7 b64 x 16 rows each
    for (int i = tid; i < 16 * 7; i += 512) {
      int r = i / 7, cb = 136 + (i - (i / 7) * 7) * 8;
      *(long long*)((char*)ssmT + SWZ256(r, cb)) = z8;
      *(long long*)((char*)TT + SWZ256(r, cb)) = z8;
    }
  }
  // sum(adj^2) stream (also warms L2 for the P7 adj fragment reads)
  float sadj2 = 0.f;
  const float* adjb = &adj[(size_t)b * N_ * N_];
  for (int q = tid; q < N_ * N_; q += 512) {
    float v = adjb[q];
    sadj2 += v * v;
  }
  // softmax rows -> ssmT (bf16), ent via m + logZ - sum(p*s)
  float entPart = 0.f;
  if (tid < N_) {
    const float* srow = &s[((size_t)b * N_ + tid) * C_];
    float sv[16], ev[16];
    float mx = -1e30f;
#pragma unroll
    for (int c = 0; c < 16; ++c) { sv[c] = srow[c]; mx = fmaxf(mx, sv[c]); }
    float sum = 0.f;
#pragma unroll
    for (int c = 0; c < 16; ++c) { ev[c] = expf(sv[c] - mx); sum += ev[c]; }
    float inv = 1.f / sum, ps = 0.f;
#pragma unroll
    for (int c = 0; c < 16; ++c) {
      float pv = ev[c] * inv;
      ps += pv * sv[c];
      *(short*)((char*)ssmT + SWZ256(c, tid * 2)) = bf16_rne(pv);
    }
    entPart = (mx + logf(sum)) - ps;
  }
  // pos passthrough (independent)
  for (int i = tid; i < N_ * FIN; i += 512)
    out[POS_OFF + (size_t)b * N_ * FIN + i] = pos[(size_t)b * N_ * FIN + i];
  __syncthreads();

  // ---- P1: layer-1 edge aggregation on [68,2] (tiny, VALU) ----
  if (tid < N_) {
    float a0 = 0, a1 = 0;
    for (int e = offs[tid]; e < offs[tid + 1]; ++e) {
      int sr = srcs[e];
      a0 += xb[sr * 2]; a1 += xb[sr * 2 + 1];
    }
    axb[tid * 2] = a0; axb[tid * 2 + 1] = a1;
  }
  __syncthreads();

  // ---- P2: layer 1 (K=2, VALU) -> Hn root-half + HT ----
  {
    float wr0 = W1r[f * 2], wr1 = W1r[f * 2 + 1];
    float wo0 = W1o[f * 2], wo1 = W1o[f * 2 + 1];
    float bv = b1[f];
    for (int i = 0; i < 17; ++i) {
      int n = ng * 17 + i;
      float v = axb[n * 2] * wr0 + axb[n * 2 + 1] * wr1 + xb[n * 2] * wo0 + xb[n * 2 + 1] * wo1 + bv;
      v = v > 0.f ? v : 0.f;
      short hv = bf16_rne(v);
      *(short*)((char*)Hn + SWZ512(n, 256 + f * 2)) = hv;
      *(short*)((char*)HT + SWZH(f, n * 2)) = hv;
    }
  }
  __syncthreads();

  // ---- P3: agg2^T = h1^T @ Ag^T (swapped operands) -> Hn agg-half, b64 epilogue ----
  // D[f][n]: A = HT row (j0+l15) k=m contig; B = Ag row (nt*16+l15) k=m contig (global agw).
  // D cols n>=68 are zero (Ag rows 68-79 zero) -> unconditional writes safe.
  {
    bf16x8 hA[3];
#pragma unroll
    for (int ks = 0; ks < 3; ++ks)
      hA[ks] = *(const bf16x8*)((const char*)HT + SWZH(j0 + l15, ks * 64 + 16 * lg));
#pragma unroll
    for (int nt = 0; nt < 5; ++nt) {
      f32x4 acc = {0.f, 0.f, 0.f, 0.f};
#pragma unroll
      for (int ks = 0; ks < 3; ++ks)
        acc = MFMA16(hA[ks], *(const bf16x8*)(agw + (nt * 16 + l15) * 128 + ks * 32 + lg * 8), acc);
      // D: col = n = nt*16+l15, row = f = j0 + lg*4 + r -> Hn[n][f..f+3] contiguous
      *(short4*)((char*)Hn + SWZ512(nt * 16 + l15, (j0 + lg * 4) * 2)) = pack4(acc);
    }
  }
  __syncthreads();

  // ---- P4: layer 2 (MFMA, K=256), deferred epilogue -> Hn root (b16) + HT (b64) ----
  {
    f32x4 accL[5];
    bf16x8 Bw[8];
#pragma unroll
    for (int ks = 0; ks < 8; ++ks)
      Bw[ks] = *(const bf16x8*)(wcat + (j0 + l15) * 256 + ks * 32 + 8 * lg);
#pragma unroll
    for (int mt = 0; mt < 5; ++mt) {
      f32x4 acc = {0.f, 0.f, 0.f, 0.f};
#pragma unroll
      for (int ks = 0; ks < 8; ++ks)
        acc = MFMA16(*(const bf16x8*)((const char*)Hn + SWZ512(mt * 16 + l15, ks * 64 + 16 * lg)), Bw[ks], acc);
      accL[mt] = acc;
    }
    __syncthreads();   // all Hn reads done
    float bv = b2f[j0 + l15];
#pragma unroll
    for (int mt = 0; mt < 5; ++mt) {
      f32x4 v;
#pragma unroll
      for (int r = 0; r < 4; ++r) {
        float t = accL[mt][r] + bv;
        v[r] = t > 0.f ? t : 0.f;
      }
      short4 p = pack4(v);
      // node-major: rows n = mt*16+lg*4+r, col j0+l15 (strided b16; rows 68-79 harmless)
      *(short*)((char*)Hn + SWZ512(mt * 16 + lg * 4 + 0, 256 + (j0 + l15) * 2)) = p.x;
      *(short*)((char*)Hn + SWZ512(mt * 16 + lg * 4 + 1, 256 + (j0 + l15) * 2)) = p.y;
      *(short*)((char*)Hn + SWZ512(mt * 16 + lg * 4 + 2, 256 + (j0 + l15) * 2)) = p.z;
      *(short*)((char*)Hn + SWZ512(mt * 16 + lg * 4 + 3, 256 + (j0 + l15) * 2)) = p.w;
      // feature-major: HT[j0+l15][n..n+3] contiguous -> b64 (cols 68-79 finite, killed by Ag/ssmT zeros)
      *(short4*)((char*)HT + SWZH(j0 + l15, (mt * 16 + lg * 4) * 2)) = p;
    }
  }
  __syncthreads();

  // ---- P5: agg3^T = h2^T @ Ag^T -> Hn agg-half, b64 epilogue ----
  {
    bf16x8 hA[3];
#pragma unroll
    for (int ks = 0; ks < 3; ++ks)
      hA[ks] = *(const bf16x8*)((const char*)HT + SWZH(j0 + l15, ks * 64 + 16 * lg));
#pragma unroll
    for (int nt = 0; nt < 5; ++nt) {
      f32x4 acc = {0.f, 0.f, 0.f, 0.f};
#pragma unroll
      for (int ks = 0; ks < 3; ++ks)
        acc = MFMA16(hA[ks], *(const bf16x8*)(agw + (nt * 16 + l15) * 128 + ks * 32 + lg * 8), acc);
      *(short4*)((char*)Hn + SWZ512(nt * 16 + l15, (j0 + lg * 4) * 2)) = pack4(acc);
    }
  }
  __syncthreads();

  // ---- P6: layer 3 (MFMA), deferred epilogue -> HT only (b64) ----
  {
    f32x4 accL[5];
    bf16x8 Bw[8];
#pragma unroll
    for (int ks = 0; ks < 8; ++ks)
      Bw[ks] = *(const bf16x8*)(wcat + 32768 + (j0 + l15) * 256 + ks * 32 + 8 * lg);
#pragma unroll
    for (int mt = 0; mt < 5; ++mt) {
      f32x4 acc = {0.f, 0.f, 0.f, 0.f};
#pragma unroll
      for (int ks = 0; ks < 8; ++ks)
        acc = MFMA16(*(const bf16x8*)((const char*)Hn + SWZ512(mt * 16 + l15, ks * 64 + 16 * lg)), Bw[ks], acc);
      accL[mt] = acc;
    }
    __syncthreads();
    float bv = b3f[j0 + l15];
#pragma unroll
    for (int mt = 0; mt < 5; ++mt) {
      f32x4 v;
#pragma unroll
      for (int r = 0; r < 4; ++r) {
        float t = accL[mt][r] + bv;
        v[r] = t > 0.f ? t : 0.f;
      }
      *(short4*)((char*)HT + SWZH(j0 + l15, (mt * 16 + lg * 4) * 2)) = pack4(v);
    }
  }
  __syncthreads();

  // ---- P7: pooling MFMAs ----
  float trPart = 0.f, g2Part = 0.f;
  {
    // pooled out (all waves): outT[f][c] = sum_n h3T[f][n] * S[n][c]
    f32x4 acc = {0.f, 0.f, 0.f, 0.f};
#pragma unroll
    for (int ks = 0; ks < 3; ++ks)
      acc = MFMA16(*(const bf16x8*)((const char*)HT + SWZH(j0 + l15, ks * 64 + 16 * lg)),
                   *(const bf16x8*)((const char*)ssmT + SWZ256(l15, ks * 64 + 16 * lg)), acc);
    float4 st; st.x = acc[0]; st.y = acc[1]; st.z = acc[2]; st.w = acc[3];
    *(float4*)&out[OUT_OFF + (size_t)b * C_ * F_ + l15 * F_ + j0 + lg * 4] = st;
  }
  if (wave < 5) {
    // T = adj @ S -> TT[c][n]; adj A-frags direct from global (row clamp for OOB)
    int row = wave * 16 + l15;
    const float* rowp = adjb + (size_t)(row < N_ ? row : 0) * N_;
    f32x4 acc = {0.f, 0.f, 0.f, 0.f};
#pragma unroll
    for (int ks = 0; ks < 3; ++ks)
      acc = MFMA16(adj_frag(rowp, ks * 32 + lg * 8),
                   *(const bf16x8*)((const char*)ssmT + SWZ256(l15, ks * 64 + 16 * lg)), acc);
#pragma unroll
    for (int r = 0; r < 4; ++r) {
      int n = wave * 16 + lg * 4 + r;
      if (n < N_) *(short*)((char*)TT + SWZ256(l15, n * 2)) = bf16_rne(acc[r]);
    }
  } else if (wave == 5) {
    // G = S^T S ; ||G||_F^2
    f32x4 acc = {0.f, 0.f, 0.f, 0.f};
#pragma unroll
    for (int ks = 0; ks < 3; ++ks) {
      bf16x8 a = *(const bf16x8*)((const char*)ssmT + SWZ256(l15, ks * 64 + 16 * lg));
      acc = MFMA16(a, a, acc);
    }
#pragma unroll
    for (int r = 0; r < 4; ++r) g2Part += acc[r] * acc[r];
  }
  __syncthreads();

  // ---- P8: out_adj = S^T T (wave 0) + trace ----
  if (wave == 0) {
    f32x4 acc = {0.f, 0.f, 0.f, 0.f};
#pragma unroll
    for (int ks = 0; ks < 3; ++ks)
      acc = MFMA16(*(const bf16x8*)((const char*)ssmT + SWZ256(l15, ks * 64 + 16 * lg)),
                   *(const bf16x8*)((const char*)TT + SWZ256(l15, ks * 64 + 16 * lg)), acc);
#pragma unroll
    for (int r = 0; r < 4; ++r) {
      int c = lg * 4 + r;
      out[ADJ_OFF + (size_t)b * 256 + c * 16 + l15] = acc[r];
      if (c == l15) trPart += acc[r];
    }
  }

  // ---- P9: loss reductions: link = sum(adj^2) - 2*tr + ||G||^2 ----
  double lk = (double)sadj2 - 2.0 * (double)trPart + (double)g2Part;
  double en = (double)entPart;
  for (int o = 32; o > 0; o >>= 1) { lk += __shfl_down(lk, o); en += __shfl_down(en, o); }
  if ((tid & 63) == 0) { red[wave] = lk; red[8 + wave] = en; }
  __syncthreads();
  if (tid == 0) {
    double L = 0, En = 0;
    for (int w = 0; w < 8; ++w) { L += red[w]; En += red[8 + w]; }
    partials[2 * b] = L;
    partials[2 * b + 1] = En;
  }
}

__global__ void finalize_kernel(const double* __restrict__ partials, float* __restrict__ out) {
  __shared__ double red[16];
  int tid = threadIdx.x;
  double L = 0, En = 0;
  for (int i = tid; i < B_; i += 512) { L += partials[2 * i]; En += partials[2 * i + 1]; }
  for (int o = 32; o > 0; o >>= 1) { L += __shfl_down(L, o); En += __shfl_down(En, o); }
  if ((tid & 63) == 0) { red[tid >> 6] = L; red[8 + (tid >> 6)] = En; }
  __syncthreads();
  if (tid == 0) {
    double Ls = 0, Es = 0;
    for (int w = 0; w < 8; ++w) { Ls += red[w]; Es += red[8 + w]; }
    out[LINK_IDX] = (float)(sqrt(Ls) / (double)((size_t)B_ * N_ * N_));
    out[ENT_IDX] = (float)(Es / (double)((size_t)B_ * N_));
  }
}

extern "C" void kernel_launch(void* const* d_in, const int* in_sizes, int n_in,
                              void* d_out, int out_size, void* d_ws, size_t ws_size,
                              hipStream_t stream) {
  const float* x   = (const float*)d_in[0];
  const int*   ei  = (const int*)d_in[1];
  const float* adj = (const float*)d_in[2];
  const float* s   = (const float*)d_in[3];
  const float* pos = (const float*)d_in[4];
  const float* W1r = (const float*)d_in[5];
  const float* W1o = (const float*)d_in[6];
  const float* b1  = (const float*)d_in[7];
  const float* W2r = (const float*)d_in[8];
  const float* W2o = (const float*)d_in[9];
  const float* b2  = (const float*)d_in[10];
  const float* W3r = (const float*)d_in[11];
  const float* W3o = (const float*)d_in[12];
  const float* b3  = (const float*)d_in[13];

  float* out = (float*)d_out;
  double* partials = (double*)d_ws;
  int* csr = (int*)((char*)d_ws + WS_CSR_OFF);
  short* wcat = (short*)((char*)d_ws + WS_W_OFF);
  short* agw  = (short*)((char*)d_ws + WS_AG_OFF);

  prep_kernel<<<65, 512, 0, stream>>>(ei, W2r, W2o, W3r, W3o, csr, wcat, agw);
  fused_kernel<<<B_, 512, 0, stream>>>(x, adj, s, pos, W1r, W1o, b1, b2, b3,
                                       wcat, agw, out, csr, partials);
  finalize_kernel<<<1, 512, 0, stream>>>(partials, out);
}

// Round 7
// 520.928 us; speedup vs baseline: 1.2323x; 1.1349x over previous
//
#include <hip/hip_runtime.h>
#include <math.h>

#define B_   8192
#define N_   68
#define FIN  2
#define F_   128
#define C_   16
#define E_   272

// d_out flat layout (fp32), reference tuple order:
#define OUT_OFF  0                              // [B,16,128]
#define ADJ_OFF  (B_*C_*F_)                     // [B,16,16]
#define LINK_IDX (ADJ_OFF + B_*C_*C_)
#define ENT_IDX  (LINK_IDX + 1)
#define POS_OFF  (ENT_IDX + 1)                  // [B,68,2]

// ws: [0,131072) partials (doubles, 8192*2)
//     [131072,+1364) csr ints
//     [133120,+131072) wcat bf16 (2 layers * 128 j * 256 k)
//     [264192,+20480) Ag bf16 [80][128] (graph multiplicity, zero rows/cols >= 68)
#define WS_CSR_OFF  131072
#define WS_W_OFF    133120
#define WS_AG_OFF   264192

typedef __attribute__((ext_vector_type(8))) short bf16x8;
typedef __attribute__((ext_vector_type(4))) float f32x4;

// XOR swizzles (T2). Row strides 512/256/192 B; XOR bits 4-5 only.
#define SWZ256(r, cb) (((r) * 256) + ((cb) ^ (((r) & 7) << 4)))
#define SWZ512(r, cb) (((r) * 512) + ((cb) ^ (((r) & 7) << 4)))
#define SWZH(r, cb)   (((r) * 192) + ((cb) ^ (((r) & 3) << 4)))
#define MFMA16(a, bb, c) __builtin_amdgcn_mfma_f32_16x16x32_bf16((a), (bb), (c), 0, 0, 0)

__device__ __forceinline__ short bf16_rne(float x) {
  unsigned u = __builtin_bit_cast(unsigned, x);
  u += 0x7FFFu + ((u >> 16) & 1u);
  return (short)(u >> 16);
}
__device__ __forceinline__ short4 pack4(f32x4 v) {
  short4 s;
  s.x = bf16_rne(v[0]); s.y = bf16_rne(v[1]); s.z = bf16_rne(v[2]); s.w = bf16_rne(v[3]);
  return s;
}

__global__ void prep_kernel(const int* __restrict__ edge_index,
                            const float* __restrict__ W2r, const float* __restrict__ W2o,
                            const float* __restrict__ W3r, const float* __restrict__ W3o,
                            int* __restrict__ csr, short* __restrict__ wcat,
                            short* __restrict__ agw) {
  int gid = blockIdx.x * blockDim.x + threadIdx.x;
  for (int e = gid; e < 2 * F_ * 256; e += gridDim.x * blockDim.x) {
    int layer = e >> 15, idx = e & 32767;
    int j = idx >> 8, k = idx & 255;
    const float* Wr = layer ? W3r : W2r;
    const float* Wo = layer ? W3o : W2o;
    float v = (k < F_) ? Wr[j * F_ + k] : Wo[j * F_ + (k - F_)];
    wcat[e] = bf16_rne(v);
  }
  __shared__ unsigned short cnt[80 * 128];
  __shared__ int src_s[E_], dst_s[E_], cc[N_], offs[N_ + 1];
  if (blockIdx.x == 0) {
    int t = threadIdx.x;
    for (int i = t; i < 80 * 128; i += blockDim.x) cnt[i] = 0;
    for (int e = t; e < E_; e += blockDim.x) { src_s[e] = edge_index[e]; dst_s[e] = edge_index[E_ + e]; }
    for (int n = t; n < N_; n += blockDim.x) cc[n] = 0;
    __syncthreads();
    if (t == 0) {
      for (int e = 0; e < E_; ++e) { cnt[dst_s[e] * 128 + src_s[e]]++; cc[dst_s[e]]++; }
      offs[0] = 0;
      for (int n = 0; n < N_; ++n) offs[n + 1] = offs[n] + cc[n];
      for (int n = 0; n < N_; ++n) cc[n] = offs[n];
      for (int e = 0; e < E_; ++e) { int d = dst_s[e]; csr[N_ + 1 + cc[d]++] = src_s[e]; }
      for (int n = 0; n <= N_; ++n) csr[n] = offs[n];
    }
    __syncthreads();
    for (int i = t; i < 80 * 128; i += blockDim.x) agw[i] = bf16_rne((float)cnt[i]);
  }
}

// ================= Kernel A: 3 GraphConv layers + pooled out =================
__launch_bounds__(512, 4)
__global__ void layers_kernel(
    const float* __restrict__ x, const float* __restrict__ s,
    const float* __restrict__ W1r, const float* __restrict__ W1o, const float* __restrict__ b1,
    const float* __restrict__ b2f, const float* __restrict__ b3f,
    const short* __restrict__ wcat, const short* __restrict__ agw,
    float* __restrict__ out, const int* __restrict__ csr)
{
  __shared__ __align__(16) short Hn[80 * 256];    // [n][0..127]=agg, [128..255]=h
  __shared__ __align__(16) short HT[128 * 96];    // h^T [f][n], stride 192B
  __shared__ __align__(16) short ssmT[16 * 128];  // softmax(s)^T [c][n], zero-pad n>=68
  __shared__ float xb[N_ * FIN], axb[N_ * FIN];
  __shared__ int offs[N_ + 1], srcs[E_];

  const int b = blockIdx.x, tid = threadIdx.x;
  const int lane = tid & 63, wave = tid >> 6;
  const int l15 = lane & 15, lg = lane >> 4;
  const int j0 = wave * 16;

  // ---- P0: fills + pad zeroing + softmax ----
  for (int i = tid; i < N_ + 1; i += 512) offs[i] = csr[i];
  for (int i = tid; i < E_; i += 512) srcs[i] = csr[N_ + 1 + i];
  for (int i = tid; i < N_ * FIN; i += 512) xb[i] = x[(size_t)b * N_ * FIN + i];
  {
    int4 zz; zz.x = 0; zz.y = 0; zz.z = 0; zz.w = 0;
    for (int i = tid; i < 384; i += 512) {          // Hn rows 68-79
      int r = 68 + (i >> 5), cb = (i & 31) * 16;
      *(int4*)((char*)Hn + SWZ512(r, cb)) = zz;
    }
    long long z8 = 0;
    for (int i = tid; i < 128 * 7; i += 512) {      // HT cols [68,96)
      int r = i / 7, cb = 136 + (i % 7) * 8;
      *(long long*)((char*)HT + SWZH(r, cb)) = z8;
    }
    for (int i = tid; i < 16 * 7; i += 512) {       // ssmT cols [68,96)
      int r = i / 7, cb = 136 + (i % 7) * 8;
      *(long long*)((char*)ssmT + SWZ256(r, cb)) = z8;
    }
  }
  if (tid < N_) {
    const float* srow = &s[((size_t)b * N_ + tid) * C_];
    float sv[16];
    float mx = -1e30f;
#pragma unroll
    for (int c = 0; c < 16; ++c) { sv[c] = srow[c]; mx = fmaxf(mx, sv[c]); }
    float sum = 0.f;
#pragma unroll
    for (int c = 0; c < 16; ++c) { sv[c] = expf(sv[c] - mx); sum += sv[c]; }
    float inv = 1.f / sum;
#pragma unroll
    for (int c = 0; c < 16; ++c)
      *(short*)((char*)ssmT + SWZ256(c, tid * 2)) = bf16_rne(sv[c] * inv);
  }
  __syncthreads();

  // ---- P1: layer-1 edge aggregation on [68,2] ----
  if (tid < N_) {
    float a0 = 0, a1 = 0;
    for (int e = offs[tid]; e < offs[tid + 1]; ++e) {
      int sr = srcs[e];
      a0 += xb[sr * 2]; a1 += xb[sr * 2 + 1];
    }
    axb[tid * 2] = a0; axb[tid * 2 + 1] = a1;
  }
  __syncthreads();

  // ---- P2a: layer 1 -> Hn h-half (row-contig b64) ----
  {
    int f4 = (tid & 31) * 4;
    float4 R0 = *(const float4*)&W1r[f4 * 2], R1 = *(const float4*)&W1r[f4 * 2 + 4];
    float4 O0 = *(const float4*)&W1o[f4 * 2], O1 = *(const float4*)&W1o[f4 * 2 + 4];
    float4 Bv = *(const float4*)&b1[f4];
#pragma unroll
    for (int p = 0; p < 5; ++p) {
      int n = p * 16 + (tid >> 5);
      if (n < N_) {
        float a0 = axb[n * 2], a1 = axb[n * 2 + 1], x0 = xb[n * 2], x1 = xb[n * 2 + 1];
        f32x4 v;
        v[0] = fmaxf(a0 * R0.x + a1 * R0.y + x0 * O0.x + x1 * O0.y + Bv.x, 0.f);
        v[1] = fmaxf(a0 * R0.z + a1 * R0.w + x0 * O0.z + x1 * O0.w + Bv.y, 0.f);
        v[2] = fmaxf(a0 * R1.x + a1 * R1.y + x0 * O1.x + x1 * O1.y + Bv.z, 0.f);
        v[3] = fmaxf(a0 * R1.z + a1 * R1.w + x0 * O1.z + x1 * O1.w + Bv.w, 0.f);
        *(short4*)((char*)Hn + SWZ512(n, 256 + f4 * 2)) = pack4(v);
      }
    }
  }
  // ---- P2b: layer 1 -> HT, WAVE-LOCAL rows (wave w writes f in [16w,16w+16)) ----
  {
    int f = tid >> 2, nq = tid & 3;
    float wr0 = W1r[f * 2], wr1 = W1r[f * 2 + 1];
    float wo0 = W1o[f * 2], wo1 = W1o[f * 2 + 1];
    float bv = b1[f];
#pragma unroll
    for (int p = 0; p < 5; ++p) {
      int n0 = p * 16 + nq * 4;
      if (n0 < N_) {
        f32x4 Aa = *(const f32x4*)&axb[n0 * 2], Ab = *(const f32x4*)&axb[n0 * 2 + 4];
        f32x4 Xa = *(const f32x4*)&xb[n0 * 2],  Xb = *(const f32x4*)&xb[n0 * 2 + 4];
        f32x4 v;
        v[0] = fmaxf(Aa[0] * wr0 + Aa[1] * wr1 + Xa[0] * wo0 + Xa[1] * wo1 + bv, 0.f);
        v[1] = fmaxf(Aa[2] * wr0 + Aa[3] * wr1 + Xa[2] * wo0 + Xa[3] * wo1 + bv, 0.f);
        v[2] = fmaxf(Ab[0] * wr0 + Ab[1] * wr1 + Xb[0] * wo0 + Xb[1] * wo1 + bv, 0.f);
        v[3] = fmaxf(Ab[2] * wr0 + Ab[3] * wr1 + Xb[2] * wo0 + Xb[3] * wo1 + bv, 0.f);
        *(short4*)((char*)HT + SWZH(f, n0 * 2)) = pack4(v);
      }
    }
  }
  // no barrier: P3 reads only wave-local HT rows (same-wave LDS is program-ordered)

  // ---- P3: agg2^T = h1^T @ Ag^T -> Hn agg-half (b64) ----
  {
    bf16x8 hA[3];
#pragma unroll
    for (int ks = 0; ks < 3; ++ks)
      hA[ks] = *(const bf16x8*)((const char*)HT + SWZH(j0 + l15, ks * 64 + 16 * lg));
#pragma unroll
    for (int nt = 0; nt < 5; ++nt) {
      f32x4 acc = {0.f, 0.f, 0.f, 0.f};
#pragma unroll
      for (int ks = 0; ks < 3; ++ks)
        acc = MFMA16(hA[ks], *(const bf16x8*)(agw + (nt * 16 + l15) * 128 + ks * 32 + lg * 8), acc);
      *(short4*)((char*)Hn + SWZ512(nt * 16 + l15, (j0 + lg * 4) * 2)) = pack4(acc);
    }
  }
  __syncthreads();

  // ---- P4: layer 2 (K=256), deferred epilogue -> Hn h-half + wave-local HT ----
  {
    f32x4 accL[5];
    bf16x8 Bw[8];
#pragma unroll
    for (int ks = 0; ks < 8; ++ks)
      Bw[ks] = *(const bf16x8*)(wcat + (j0 + l15) * 256 + ks * 32 + 8 * lg);
#pragma unroll
    for (int mt = 0; mt < 5; ++mt) {
      f32x4 acc = {0.f, 0.f, 0.f, 0.f};
#pragma unroll
      for (int ks = 0; ks < 8; ++ks)
        acc = MFMA16(*(const bf16x8*)((const char*)Hn + SWZ512(mt * 16 + l15, ks * 64 + 16 * lg)), Bw[ks], acc);
      accL[mt] = acc;
    }
    __syncthreads();   // all Hn reads done before Hn writes below
    float bv = b2f[j0 + l15];
#pragma unroll
    for (int mt = 0; mt < 5; ++mt) {
      f32x4 v;
#pragma unroll
      for (int r = 0; r < 4; ++r) {
        float t = accL[mt][r] + bv;
        v[r] = t > 0.f ? t : 0.f;
      }
      short4 p = pack4(v);
      *(short*)((char*)Hn + SWZ512(mt * 16 + lg * 4 + 0, 256 + (j0 + l15) * 2)) = p.x;
      *(short*)((char*)Hn + SWZ512(mt * 16 + lg * 4 + 1, 256 + (j0 + l15) * 2)) = p.y;
      *(short*)((char*)Hn + SWZ512(mt * 16 + lg * 4 + 2, 256 + (j0 + l15) * 2)) = p.z;
      *(short*)((char*)Hn + SWZ512(mt * 16 + lg * 4 + 3, 256 + (j0 + l15) * 2)) = p.w;
      *(short4*)((char*)HT + SWZH(j0 + l15, (mt * 16 + lg * 4) * 2)) = p;  // wave-local row
    }
  }
  // no barrier: P5 reads only wave-local HT rows

  // ---- P5: agg3^T = h2^T @ Ag^T -> Hn agg-half ----
  {
    bf16x8 hA[3];
#pragma unroll
    for (int ks = 0; ks < 3; ++ks)
      hA[ks] = *(const bf16x8*)((const char*)HT + SWZH(j0 + l15, ks * 64 + 16 * lg));
#pragma unroll
    for (int nt = 0; nt < 5; ++nt) {
      f32x4 acc = {0.f, 0.f, 0.f, 0.f};
#pragma unroll
      for (int ks = 0; ks < 3; ++ks)
        acc = MFMA16(hA[ks], *(const bf16x8*)(agw + (nt * 16 + l15) * 128 + ks * 32 + lg * 8), acc);
      *(short4*)((char*)Hn + SWZ512(nt * 16 + l15, (j0 + lg * 4) * 2)) = pack4(acc);
    }
  }
  __syncthreads();

  // ---- P6: layer 3 -> wave-local HT rows (no mid barrier: no shared writes) ----
  {
    bf16x8 Bw[8];
#pragma unroll
    for (int ks = 0; ks < 8; ++ks)
      Bw[ks] = *(const bf16x8*)(wcat + 32768 + (j0 + l15) * 256 + ks * 32 + 8 * lg);
    float bv = b3f[j0 + l15];
#pragma unroll
    for (int mt = 0; mt < 5; ++mt) {
      f32x4 acc = {0.f, 0.f, 0.f, 0.f};
#pragma unroll
      for (int ks = 0; ks < 8; ++ks)
        acc = MFMA16(*(const bf16x8*)((const char*)Hn + SWZ512(mt * 16 + l15, ks * 64 + 16 * lg)), Bw[ks], acc);
      f32x4 v;
#pragma unroll
      for (int r = 0; r < 4; ++r) {
        float t = acc[r] + bv;
        v[r] = t > 0.f ? t : 0.f;
      }
      *(short4*)((char*)HT + SWZH(j0 + l15, (mt * 16 + lg * 4) * 2)) = pack4(v);
    }
  }
  // no barrier: P7a reads only wave-local HT rows + ssmT (written pre-P1 barrier)

  // ---- P7a: pooled out: outT[f][c] = sum_n h3T[f][n] * S[n][c] ----
  {
    f32x4 acc = {0.f, 0.f, 0.f, 0.f};
#pragma unroll
    for (int ks = 0; ks < 3; ++ks)
      acc = MFMA16(*(const bf16x8*)((const char*)HT + SWZH(j0 + l15, ks * 64 + 16 * lg)),
                   *(const bf16x8*)((const char*)ssmT + SWZ256(l15, ks * 64 + 16 * lg)), acc);
    float4 st; st.x = acc[0]; st.y = acc[1]; st.z = acc[2]; st.w = acc[3];
    *(float4*)&out[OUT_OFF + (size_t)b * C_ * F_ + l15 * F_ + j0 + lg * 4] = st;
  }
}

// ================= Kernel B: adj pooling + losses + pos =================
__launch_bounds__(512, 4)
__global__ void pool_kernel(
    const float* __restrict__ adj, const float* __restrict__ s, const float* __restrict__ pos,
    float* __restrict__ out, double* __restrict__ partials)
{
  __shared__ __align__(16) short AdjB[80 * 128];  // adj bf16 [n][m], zero-padded
  __shared__ __align__(16) short ssmT[16 * 128];  // softmax(s)^T [c][n]
  __shared__ __align__(16) short TT[16 * 128];    // (adj@S)^T [c][n]
  __shared__ double red[16];

  const int b = blockIdx.x, tid = threadIdx.x;
  const int lane = tid & 63, wave = tid >> 6;
  const int l15 = lane & 15, lg = lane >> 4;

  // ---- P0: zero pads (disjoint from fills) + fills ----
  {
    long long z8 = 0;
    // AdjB logical cols [68,128) all 80 rows: 15 b64 per row
    for (int i = tid; i < 1200; i += 512) {
      int r = i / 15, cb = 136 + (i % 15) * 8;
      *(long long*)((char*)AdjB + SWZ256(r, cb)) = z8;
    }
    // AdjB rows 68-79 cols [0,68): 17 b64 per row
    for (int i = tid; i < 204; i += 512) {
      int r = 68 + i / 17, cb = (i % 17) * 8;
      *(long long*)((char*)AdjB + SWZ256(r, cb)) = z8;
    }
    // ssmT/TT cols [68,96)
    for (int i = tid; i < 16 * 7; i += 512) {
      int r = i / 7, cb = 136 + (i % 7) * 8;
      *(long long*)((char*)ssmT + SWZ256(r, cb)) = z8;
      *(long long*)((char*)TT + SWZ256(r, cb)) = z8;
    }
  }
  float sadj2 = 0.f;
  const float* adjb = &adj[(size_t)b * N_ * N_];
  for (int q = tid; q < N_ * N_; q += 512) {
    int n = q / N_, m = q - n * N_;
    float v = adjb[q];
    sadj2 += v * v;
    *(short*)((char*)AdjB + SWZ256(n, m * 2)) = bf16_rne(v);
  }
  float entPart = 0.f;
  if (tid < N_) {
    const float* srow = &s[((size_t)b * N_ + tid) * C_];
    float sv[16], ev[16];
    float mx = -1e30f;
#pragma unroll
    for (int c = 0; c < 16; ++c) { sv[c] = srow[c]; mx = fmaxf(mx, sv[c]); }
    float sum = 0.f;
#pragma unroll
    for (int c = 0; c < 16; ++c) { ev[c] = expf(sv[c] - mx); sum += ev[c]; }
    float inv = 1.f / sum, ps = 0.f;
#pragma unroll
    for (int c = 0; c < 16; ++c) {
      float pv = ev[c] * inv;
      ps += pv * sv[c];
      *(short*)((char*)ssmT + SWZ256(c, tid * 2)) = bf16_rne(pv);
    }
    entPart = (mx + logf(sum)) - ps;
  }
  for (int i = tid; i < N_ * FIN; i += 512)
    out[POS_OFF + (size_t)b * N_ * FIN + i] = pos[(size_t)b * N_ * FIN + i];
  __syncthreads();

  // ---- P1: T = adj@S (waves 0-4), G = S^T S (wave 5) ----
  float g2Part = 0.f;
  if (wave < 5) {
    f32x4 acc = {0.f, 0.f, 0.f, 0.f};
#pragma unroll
    for (int ks = 0; ks < 3; ++ks)
      acc = MFMA16(*(const bf16x8*)((const char*)AdjB + SWZ256(wave * 16 + l15, ks * 64 + 16 * lg)),
                   *(const bf16x8*)((const char*)ssmT + SWZ256(l15, ks * 64 + 16 * lg)), acc);
#pragma unroll
    for (int r = 0; r < 4; ++r) {
      int n = wave * 16 + lg * 4 + r;
      if (n < N_) *(short*)((char*)TT + SWZ256(l15, n * 2)) = bf16_rne(acc[r]);
    }
  } else if (wave == 5) {
    f32x4 acc = {0.f, 0.f, 0.f, 0.f};
#pragma unroll
    for (int ks = 0; ks < 3; ++ks) {
      bf16x8 a = *(const bf16x8*)((const char*)ssmT + SWZ256(l15, ks * 64 + 16 * lg));
      acc = MFMA16(a, a, acc);
    }
#pragma unroll
    for (int r = 0; r < 4; ++r) g2Part += acc[r] * acc[r];
  }
  __syncthreads();

  // ---- P2: out_adj = S^T T (wave 0) + trace ----
  float trPart = 0.f;
  if (wave == 0) {
    f32x4 acc = {0.f, 0.f, 0.f, 0.f};
#pragma unroll
    for (int ks = 0; ks < 3; ++ks)
      acc = MFMA16(*(const bf16x8*)((const char*)ssmT + SWZ256(l15, ks * 64 + 16 * lg)),
                   *(const bf16x8*)((const char*)TT + SWZ256(l15, ks * 64 + 16 * lg)), acc);
#pragma unroll
    for (int r = 0; r < 4; ++r) {
      int c = lg * 4 + r;
      out[ADJ_OFF + (size_t)b * 256 + c * 16 + l15] = acc[r];
      if (c == l15) trPart += acc[r];
    }
  }

  // ---- P3: losses: link = sum(adj^2) - 2*tr + ||G||^2 ----
  double lk = (double)sadj2 - 2.0 * (double)trPart + (double)g2Part;
  double en = (double)entPart;
  for (int o = 32; o > 0; o >>= 1) { lk += __shfl_down(lk, o); en += __shfl_down(en, o); }
  if ((tid & 63) == 0) { red[wave] = lk; red[8 + wave] = en; }
  __syncthreads();
  if (tid == 0) {
    double L = 0, En = 0;
    for (int w = 0; w < 8; ++w) { L += red[w]; En += red[8 + w]; }
    partials[2 * b] = L;
    partials[2 * b + 1] = En;
  }
}

__global__ void finalize_kernel(const double* __restrict__ partials, float* __restrict__ out) {
  __shared__ double red[16];
  int tid = threadIdx.x;
  double L = 0, En = 0;
  for (int i = tid; i < B_; i += 512) { L += partials[2 * i]; En += partials[2 * i + 1]; }
  for (int o = 32; o > 0; o >>= 1) { L += __shfl_down(L, o); En += __shfl_down(En, o); }
  if ((tid & 63) == 0) { red[tid >> 6] = L; red[8 + (tid >> 6)] = En; }
  __syncthreads();
  if (tid == 0) {
    double Ls = 0, Es = 0;
    for (int w = 0; w < 8; ++w) { Ls += red[w]; Es += red[8 + w]; }
    out[LINK_IDX] = (float)(sqrt(Ls) / (double)((size_t)B_ * N_ * N_));
    out[ENT_IDX] = (float)(Es / (double)((size_t)B_ * N_));
  }
}

extern "C" void kernel_launch(void* const* d_in, const int* in_sizes, int n_in,
                              void* d_out, int out_size, void* d_ws, size_t ws_size,
                              hipStream_t stream) {
  const float* x   = (const float*)d_in[0];
  const int*   ei  = (const int*)d_in[1];
  const float* adj = (const float*)d_in[2];
  const float* s   = (const float*)d_in[3];
  const float* pos = (const float*)d_in[4];
  const float* W1r = (const float*)d_in[5];
  const float* W1o = (const float*)d_in[6];
  const float* b1  = (const float*)d_in[7];
  const float* W2r = (const float*)d_in[8];
  const float* W2o = (const float*)d_in[9];
  const float* b2  = (const float*)d_in[10];
  const float* W3r = (const float*)d_in[11];
  const float* W3o = (const float*)d_in[12];
  const float* b3  = (const float*)d_in[13];

  float* out = (float*)d_out;
  double* partials = (double*)d_ws;
  int* csr = (int*)((char*)d_ws + WS_CSR_OFF);
  short* wcat = (short*)((char*)d_ws + WS_W_OFF);
  short* agw  = (short*)((char*)d_ws + WS_AG_OFF);

  prep_kernel<<<65, 512, 0, stream>>>(ei, W2r, W2o, W3r, W3o, csr, wcat, agw);
  layers_kernel<<<B_, 512, 0, stream>>>(x, s, W1r, W1o, b1, b2, b3, wcat, agw, out, csr);
  pool_kernel<<<B_, 512, 0, stream>>>(adj, s, pos, out, partials);
  finalize_kernel<<<1, 512, 0, stream>>>(partials, out);
}